// Round 1
// baseline (7539.536 us; speedup 1.0000x reference)
//
#include <hip/hip_runtime.h>
#include <hip/hip_bf16.h>
#include <cstdint>
#include <cstddef>

#define V_ 8192
#define D_ 1024
#define B_ 32
#define T_ 128

typedef __attribute__((ext_vector_type(8))) short bf16x8;
typedef __attribute__((ext_vector_type(4))) float f32x4;

__device__ __forceinline__ short f2bf(float f) {
  union { float f; unsigned u; } v; v.f = f;
  unsigned r = v.u + 0x7fffu + ((v.u >> 16) & 1u);
  return (short)(r >> 16);
}

// async global->LDS, 16B per lane. lds base must be wave-uniform.
__device__ __forceinline__ void lds_load16(const void* g, void* l) {
  __builtin_amdgcn_global_load_lds(
      (const __attribute__((address_space(1))) unsigned int*)g,
      (__attribute__((address_space(3))) unsigned int*)l,
      16, 0, 0);
}

// ---------- f32 -> bf16 conversion (W_ho) ----------
__global__ __launch_bounds__(256) void conv_bf16_k(const float* __restrict__ in,
                                                   short* __restrict__ out, int n4) {
  int i = blockIdx.x * 256 + threadIdx.x;  // one float4 per thread
  if (i >= n4) return;
  float4 v = reinterpret_cast<const float4*>(in)[i];
  short4 o;
  o.x = f2bf(v.x); o.y = f2bf(v.y); o.z = f2bf(v.z); o.w = f2bf(v.w);
  reinterpret_cast<short4*>(out)[i] = o;
}

// ---------- X[t,b,d] = W_ih[d, idx[b,t]] + b_ih[d] + b_hh[d] ----------
__global__ __launch_bounds__(256) void xgather(const int* __restrict__ idx,
                                               const float* __restrict__ W_ih,
                                               const float* __restrict__ b_ih,
                                               const float* __restrict__ b_hh,
                                               float* __restrict__ X) {
  int i = blockIdx.x * 256 + threadIdx.x;   // over T*B*D = 4194304
  int d = i & (D_ - 1);
  int b = (i >> 10) & (B_ - 1);
  int t = i >> 15;
  int tok = idx[b * T_ + t];
  X[i] = W_ih[(size_t)d * V_ + tok] + b_ih[d] + b_hh[d];
}

// ---------- one recurrence step: h = tanh(X_t + hprev @ W_hh^T) ----------
// grid (16, 4), block 512: block = 64 d  x  8 b
__global__ __launch_bounds__(512) void rnn_step(const float* __restrict__ hprev,
                                                const float* __restrict__ W_hh,
                                                const float* __restrict__ X_t,
                                                float* __restrict__ hout_f,
                                                short* __restrict__ hout_b) {
  __shared__ __align__(16) float hs[8][D_];   // 32 KB
  const int tid = threadIdx.x;
  const int d = blockIdx.x * 64 + (tid & 63);
  const int bl = tid >> 6;                    // 0..7 (wave id, wave-uniform)
  const int b0 = blockIdx.y * 8;

  // stage hprev chunk: 8*1024 floats = 2048 float4, 512 threads -> 4 each
#pragma unroll
  for (int i = 0; i < 4; ++i) {
    int c = tid + 512 * i;                    // float4 index, 0..2047
    int bb = c >> 8;                          // row (256 float4 per row)
    int kk = c & 255;
    *reinterpret_cast<float4*>(&hs[bb][kk * 4]) =
        *reinterpret_cast<const float4*>(&hprev[(size_t)(b0 + bb) * D_ + kk * 4]);
  }
  __syncthreads();

  const float* wrow = W_hh + (size_t)d * D_;
  float4 s = {0.f, 0.f, 0.f, 0.f};
#pragma unroll 4
  for (int k4 = 0; k4 < 256; ++k4) {
    float4 w = *reinterpret_cast<const float4*>(&wrow[k4 * 4]);
    float4 h = *reinterpret_cast<const float4*>(&hs[bl][k4 * 4]);
    s.x += w.x * h.x; s.y += w.y * h.y; s.z += w.z * h.z; s.w += w.w * h.w;
  }
  float acc = (s.x + s.y) + (s.z + s.w);
  const int b = b0 + bl;
  float hv = tanhf(X_t[(size_t)b * D_ + d] + acc);
  hout_f[(size_t)b * D_ + d] = hv;
  hout_b[(size_t)b * D_ + d] = f2bf(hv);
}

// ---------- logits GEMM: C[r, v] = sum_d Hb[r,d]*Wb[v,d] + b_o[v] ----------
// M=4096, N=8192, K=1024. bf16 MFMA 16x16x32, tile 128x128, BK=64, 4 waves.
__global__ __launch_bounds__(256) void gemm_logits(const short* __restrict__ A,
                                                   const short* __restrict__ Bt,
                                                   const float* __restrict__ b_o,
                                                   float* __restrict__ C) {
  constexpr int K = D_;
  constexpr int N = V_;
  __shared__ __align__(16) short As[128 * 64];  // 16 KB, row-major [128][64]
  __shared__ __align__(16) short Bs[128 * 64];

  const int tid = threadIdx.x;
  const int lane = tid & 63;
  const int w = tid >> 6;
  const int wr = w >> 1, wc = w & 1;
  const int r0 = blockIdx.y * 128;
  const int c0 = blockIdx.x * 128;

  f32x4 acc[4][4] = {};

  for (int k0 = 0; k0 < K; k0 += 64) {
    // stage A/B tiles: each 1024 chunks of 16B; 256 thr * 4 chunks
#pragma unroll
    for (int i = 0; i < 4; ++i) {
      int c = tid + 256 * i;                 // per-lane chunk id
      int cb = (tid & ~63) + 256 * i;        // wave-uniform chunk base
      int row = c >> 3;
      int col = (c & 7) * 8;
      lds_load16(A + (size_t)(r0 + row) * K + k0 + col, &As[cb * 8]);
      lds_load16(Bt + (size_t)(c0 + row) * K + k0 + col, &Bs[cb * 8]);
    }
    asm volatile("s_waitcnt vmcnt(0)" ::: "memory");
    __syncthreads();

#pragma unroll
    for (int kk = 0; kk < 2; ++kk) {
      bf16x8 af[4], bfr[4];
      const int kof = kk * 32 + (lane >> 4) * 8;
      const int fcol = lane & 15;
#pragma unroll
      for (int i = 0; i < 4; ++i)
        af[i] = *reinterpret_cast<const bf16x8*>(&As[(wr * 64 + i * 16 + fcol) * 64 + kof]);
#pragma unroll
      for (int j = 0; j < 4; ++j)
        bfr[j] = *reinterpret_cast<const bf16x8*>(&Bs[(wc * 64 + j * 16 + fcol) * 64 + kof]);
#pragma unroll
      for (int i = 0; i < 4; ++i)
#pragma unroll
        for (int j = 0; j < 4; ++j)
          acc[i][j] = __builtin_amdgcn_mfma_f32_16x16x32_bf16(af[i], bfr[j], acc[i][j], 0, 0, 0);
    }
    __syncthreads();
  }

  const int fcol = lane & 15;
  const int frow = (lane >> 4) * 4;
#pragma unroll
  for (int i = 0; i < 4; ++i) {
    int row = r0 + wr * 64 + i * 16 + frow;
#pragma unroll
    for (int j = 0; j < 4; ++j) {
      int col = c0 + wc * 64 + j * 16 + fcol;
      float bias = b_o[col];
#pragma unroll
      for (int q = 0; q < 4; ++q)
        C[(size_t)(row + q) * N + col] = acc[i][j][q] + bias;
    }
  }
}

// ---------- in-place log-softmax over rows of 8192 ----------
__global__ __launch_bounds__(256) void logsoftmax(float* __restrict__ out) {
  __shared__ float red[4];
  __shared__ float red2[4];
  float* row = out + (size_t)blockIdx.x * V_;
  const int tid = threadIdx.x;

  float4 v[8];
  float mx = -1e30f;
#pragma unroll
  for (int i = 0; i < 8; ++i) {
    v[i] = *reinterpret_cast<const float4*>(&row[(i * 256 + tid) * 4]);
    mx = fmaxf(mx, fmaxf(fmaxf(v[i].x, v[i].y), fmaxf(v[i].z, v[i].w)));
  }
#pragma unroll
  for (int off = 32; off > 0; off >>= 1) mx = fmaxf(mx, __shfl_xor(mx, off, 64));
  if ((tid & 63) == 0) red[tid >> 6] = mx;
  __syncthreads();
  mx = fmaxf(fmaxf(red[0], red[1]), fmaxf(red[2], red[3]));

  float sum = 0.f;
#pragma unroll
  for (int i = 0; i < 8; ++i)
    sum += expf(v[i].x - mx) + expf(v[i].y - mx) + expf(v[i].z - mx) + expf(v[i].w - mx);
#pragma unroll
  for (int off = 32; off > 0; off >>= 1) sum += __shfl_xor(sum, off, 64);
  if ((tid & 63) == 0) red2[tid >> 6] = sum;
  __syncthreads();
  sum = (red2[0] + red2[1]) + (red2[2] + red2[3]);

  const float lse = mx + logf(sum);
#pragma unroll
  for (int i = 0; i < 8; ++i) {
    float4 o = v[i];
    o.x -= lse; o.y -= lse; o.z -= lse; o.w -= lse;
    *reinterpret_cast<float4*>(&row[(i * 256 + tid) * 4]) = o;
  }
}

extern "C" void kernel_launch(void* const* d_in, const int* in_sizes, int n_in,
                              void* d_out, int out_size, void* d_ws, size_t ws_size,
                              hipStream_t stream) {
  const int* idx = (const int*)d_in[0];
  const float* h0 = (const float*)d_in[1];
  const float* W_ih = (const float*)d_in[2];
  const float* b_ih = (const float*)d_in[3];
  const float* W_hh = (const float*)d_in[4];
  const float* b_hh = (const float*)d_in[5];
  const float* W_ho = (const float*)d_in[6];
  const float* b_o = (const float*)d_in[7];
  float* out = (float*)d_out;

  // workspace layout (58.7 MB total):
  // H f32   [128][32][1024]  16 MB @ 0
  // X f32   [128][32][1024]  16 MB @ 16M
  // Hb bf16 [128][32][1024]   8 MB @ 32M
  // Wb bf16 [8192][1024]     16 MB @ 40M
  char* ws = (char*)d_ws;
  float* H = (float*)ws;
  float* X = (float*)(ws + (size_t)16 * 1024 * 1024);
  short* Hb = (short*)(ws + (size_t)32 * 1024 * 1024);
  short* Wb = (short*)(ws + (size_t)40 * 1024 * 1024);

  conv_bf16_k<<<dim3(8192), dim3(256), 0, stream>>>(W_ho, Wb, (V_ * D_) / 4);
  xgather<<<dim3(16384), dim3(256), 0, stream>>>(idx, W_ih, b_ih, b_hh, X);

  for (int t = 0; t < T_; ++t) {
    const float* hp = (t == 0) ? h0 : (H + (size_t)(t - 1) * B_ * D_);
    rnn_step<<<dim3(16, 4), dim3(512), 0, stream>>>(
        hp, W_hh, X + (size_t)t * B_ * D_,
        H + (size_t)t * B_ * D_, Hb + (size_t)t * B_ * D_);
  }

  gemm_logits<<<dim3(V_ / 128, (T_ * B_) / 128), dim3(256), 0, stream>>>(Hb, Wb, b_o, out);
  logsoftmax<<<dim3(T_ * B_), dim3(256), 0, stream>>>(out);
}

// Round 2
// 1599.404 us; speedup vs baseline: 4.7140x; 4.7140x over previous
//
#include <hip/hip_runtime.h>
#include <hip/hip_bf16.h>
#include <cstdint>
#include <cstddef>

#define V_ 8192
#define D_ 1024
#define B_ 32
#define T_ 128

typedef __attribute__((ext_vector_type(8))) short bf16x8;
typedef __attribute__((ext_vector_type(4))) float f32x4;

__device__ __forceinline__ short f2bf(float f) {
  union { float f; unsigned u; } v; v.f = f;
  unsigned r = v.u + 0x7fffu + ((v.u >> 16) & 1u);
  return (short)(r >> 16);
}

// async global->LDS, 16B per lane. lds base must be wave-uniform.
__device__ __forceinline__ void lds_load16(const void* g, void* l) {
  __builtin_amdgcn_global_load_lds(
      (const __attribute__((address_space(1))) unsigned int*)g,
      (__attribute__((address_space(3))) unsigned int*)l,
      16, 0, 0);
}

// ---------- f32 -> bf16 conversion ----------
__global__ __launch_bounds__(256) void conv_bf16_k(const float* __restrict__ in,
                                                   short* __restrict__ out, int n4) {
  int i = blockIdx.x * 256 + threadIdx.x;  // one float4 per thread
  if (i >= n4) return;
  float4 v = reinterpret_cast<const float4*>(in)[i];
  short4 o;
  o.x = f2bf(v.x); o.y = f2bf(v.y); o.z = f2bf(v.z); o.w = f2bf(v.w);
  reinterpret_cast<short4*>(out)[i] = o;
}

// ---------- W_hh split: Rb = bf16(W_hh with zeroed diag), Wdiag = diag(W_hh) f32 ----------
__global__ __launch_bounds__(256) void conv_whh(const float* __restrict__ W,
                                                short* __restrict__ Rb,
                                                float* __restrict__ Wdiag) {
  int i = blockIdx.x * 256 + threadIdx.x;   // over D*D = 1048576
  int n = i >> 10;
  int k = i & (D_ - 1);
  float w = W[i];
  Rb[i] = f2bf(k == n ? 0.0f : w);
  if (k == n) Wdiag[n] = w;
}

// ---------- h0 -> Hf buf0 (f32) + Hb slot0 (bf16) ----------
__global__ __launch_bounds__(256) void init_h(const float* __restrict__ h0,
                                              float* __restrict__ Hf0,
                                              short* __restrict__ Hb0) {
  int i = blockIdx.x * 256 + threadIdx.x;   // over 32768
  float v = h0[i];
  Hf0[i] = v;
  Hb0[i] = f2bf(v);
}

// ---------- X[t,b,d] = W_ih[d, idx[b,t]] + b_ih[d] + b_hh[d] ----------
__global__ __launch_bounds__(256) void xgather(const int* __restrict__ idx,
                                               const float* __restrict__ W_ih,
                                               const float* __restrict__ b_ih,
                                               const float* __restrict__ b_hh,
                                               float* __restrict__ X) {
  int i = blockIdx.x * 256 + threadIdx.x;   // over T*B*D = 4194304
  int d = i & (D_ - 1);
  int b = (i >> 10) & (B_ - 1);
  int t = i >> 15;
  int tok = idx[b * T_ + t];
  X[i] = W_ih[(size_t)d * V_ + tok] + b_ih[d] + b_hh[d];
}

// ---------- recurrence step via bf16 MFMA, no LDS ----------
// h_next[m,n] = tanh(X_t[m,n] + sum_k Hb_prev[m,k]*Rb[n,k] + Hf_prev[m,n]*Wdiag[n])
// grid 64 blocks x 64 threads; each wave owns 16 n, all 32 m.
__global__ __launch_bounds__(64) void rnn_step_mfma(const short* __restrict__ Hbp,
                                                    const float* __restrict__ Hfp,
                                                    const short* __restrict__ Rb,
                                                    const float* __restrict__ Wdiag,
                                                    const float* __restrict__ X_t,
                                                    short* __restrict__ Hbn,
                                                    float* __restrict__ Hfn) {
  const int lane = threadIdx.x;           // 0..63
  const int nb = blockIdx.x * 16;
  const int fcol = lane & 15;
  const int kof0 = (lane >> 4) * 8;

  f32x4 acc0 = {0.f, 0.f, 0.f, 0.f};
  f32x4 acc1 = {0.f, 0.f, 0.f, 0.f};

  const short* a0 = Hbp + (size_t)fcol * D_ + kof0;        // m rows 0..15
  const short* a1 = a0 + 16 * D_;                          // m rows 16..31
  const short* bp = Rb + (size_t)(nb + fcol) * D_ + kof0;  // n rows

#pragma unroll 4
  for (int kk = 0; kk < 32; ++kk) {
    bf16x8 af0 = *reinterpret_cast<const bf16x8*>(a0 + kk * 32);
    bf16x8 af1 = *reinterpret_cast<const bf16x8*>(a1 + kk * 32);
    bf16x8 bfv = *reinterpret_cast<const bf16x8*>(bp + kk * 32);
    acc0 = __builtin_amdgcn_mfma_f32_16x16x32_bf16(af0, bfv, acc0, 0, 0, 0);
    acc1 = __builtin_amdgcn_mfma_f32_16x16x32_bf16(af1, bfv, acc1, 0, 0, 0);
  }

  const int n = nb + fcol;
  const float wd = Wdiag[n];
  const int m0 = (lane >> 4) * 4;
#pragma unroll
  for (int q = 0; q < 4; ++q) {
    int m = m0 + q;
    float v = tanhf(X_t[m * D_ + n] + acc0[q] + Hfp[m * D_ + n] * wd);
    Hfn[m * D_ + n] = v;
    Hbn[m * D_ + n] = f2bf(v);
    m += 16;
    v = tanhf(X_t[m * D_ + n] + acc1[q] + Hfp[m * D_ + n] * wd);
    Hfn[m * D_ + n] = v;
    Hbn[m * D_ + n] = f2bf(v);
  }
}

// ---------- logits GEMM: C[r, v] = sum_d Hb[r,d]*Wb[v,d] + b_o[v] ----------
// M=4096, N=8192, K=1024. bf16 MFMA 16x16x32, tile 128x128, BK=64, 4 waves.
// LDS XOR-swizzle: chunk col ^= (row&7), applied on global SOURCE + ds_read index.
__global__ __launch_bounds__(256) void gemm_logits(const short* __restrict__ A,
                                                   const short* __restrict__ Bt,
                                                   const float* __restrict__ b_o,
                                                   float* __restrict__ C) {
  constexpr int K = D_;
  constexpr int N = V_;
  __shared__ __align__(16) short As[128 * 64];  // 16 KB, [128][8 chunks of 8 bf16]
  __shared__ __align__(16) short Bs[128 * 64];

  const int tid = threadIdx.x;
  const int lane = tid & 63;
  const int w = tid >> 6;
  const int wr = w >> 1, wc = w & 1;
  const int r0 = blockIdx.y * 128;
  const int c0 = blockIdx.x * 128;

  f32x4 acc[4][4] = {};

  for (int k0 = 0; k0 < K; k0 += 64) {
    // stage A/B tiles: each 1024 chunks of 16B; 256 thr * 4 chunks
#pragma unroll
    for (int i = 0; i < 4; ++i) {
      int c = tid + 256 * i;                 // per-lane chunk id
      int cb = (tid & ~63) + 256 * i;        // wave-uniform chunk base
      int row = c >> 3;
      int colc = ((c & 7) ^ (row & 7)) * 8;  // pre-swizzled source column
      lds_load16(A + (size_t)(r0 + row) * K + k0 + colc, &As[cb * 8]);
      lds_load16(Bt + (size_t)(c0 + row) * K + k0 + colc, &Bs[cb * 8]);
    }
    asm volatile("s_waitcnt vmcnt(0)" ::: "memory");
    __syncthreads();

#pragma unroll
    for (int kk = 0; kk < 2; ++kk) {
      bf16x8 af[4], bfr[4];
      const int fcol = lane & 15;
      const int chunk = (kk * 4 + (lane >> 4)) ^ (fcol & 7);  // swizzled read chunk
#pragma unroll
      for (int i = 0; i < 4; ++i)
        af[i] = *reinterpret_cast<const bf16x8*>(&As[(wr * 64 + i * 16 + fcol) * 64 + chunk * 8]);
#pragma unroll
      for (int j = 0; j < 4; ++j)
        bfr[j] = *reinterpret_cast<const bf16x8*>(&Bs[(wc * 64 + j * 16 + fcol) * 64 + chunk * 8]);
#pragma unroll
      for (int i = 0; i < 4; ++i)
#pragma unroll
        for (int j = 0; j < 4; ++j)
          acc[i][j] = __builtin_amdgcn_mfma_f32_16x16x32_bf16(af[i], bfr[j], acc[i][j], 0, 0, 0);
    }
    __syncthreads();
  }

  const int fcol = lane & 15;
  const int frow = (lane >> 4) * 4;
#pragma unroll
  for (int i = 0; i < 4; ++i) {
    int row = r0 + wr * 64 + i * 16 + frow;
#pragma unroll
    for (int j = 0; j < 4; ++j) {
      int col = c0 + wc * 64 + j * 16 + fcol;
      float bias = b_o[col];
#pragma unroll
      for (int q = 0; q < 4; ++q)
        C[(size_t)(row + q) * N + col] = acc[i][j][q] + bias;
    }
  }
}

// ---------- in-place log-softmax over rows of 8192 ----------
__global__ __launch_bounds__(256) void logsoftmax(float* __restrict__ out) {
  __shared__ float red[4];
  __shared__ float red2[4];
  float* row = out + (size_t)blockIdx.x * V_;
  const int tid = threadIdx.x;

  float4 v[8];
  float mx = -1e30f;
#pragma unroll
  for (int i = 0; i < 8; ++i) {
    v[i] = *reinterpret_cast<const float4*>(&row[(i * 256 + tid) * 4]);
    mx = fmaxf(mx, fmaxf(fmaxf(v[i].x, v[i].y), fmaxf(v[i].z, v[i].w)));
  }
#pragma unroll
  for (int off = 32; off > 0; off >>= 1) mx = fmaxf(mx, __shfl_xor(mx, off, 64));
  if ((tid & 63) == 0) red[tid >> 6] = mx;
  __syncthreads();
  mx = fmaxf(fmaxf(red[0], red[1]), fmaxf(red[2], red[3]));

  float sum = 0.f;
#pragma unroll
  for (int i = 0; i < 8; ++i)
    sum += expf(v[i].x - mx) + expf(v[i].y - mx) + expf(v[i].z - mx) + expf(v[i].w - mx);
#pragma unroll
  for (int off = 32; off > 0; off >>= 1) sum += __shfl_xor(sum, off, 64);
  if ((tid & 63) == 0) red2[tid >> 6] = sum;
  __syncthreads();
  sum = (red2[0] + red2[1]) + (red2[2] + red2[3]);

  const float lse = mx + logf(sum);
#pragma unroll
  for (int i = 0; i < 8; ++i) {
    float4 o = v[i];
    o.x -= lse; o.y -= lse; o.z -= lse; o.w -= lse;
    *reinterpret_cast<float4*>(&row[(i * 256 + tid) * 4]) = o;
  }
}

extern "C" void kernel_launch(void* const* d_in, const int* in_sizes, int n_in,
                              void* d_out, int out_size, void* d_ws, size_t ws_size,
                              hipStream_t stream) {
  const int* idx = (const int*)d_in[0];
  const float* h0 = (const float*)d_in[1];
  const float* W_ih = (const float*)d_in[2];
  const float* b_ih = (const float*)d_in[3];
  const float* W_hh = (const float*)d_in[4];
  const float* b_hh = (const float*)d_in[5];
  const float* W_ho = (const float*)d_in[6];
  const float* b_o = (const float*)d_in[7];
  float* out = (float*)d_out;

  // workspace layout (~42.3 MB):
  // X  f32  [128][32][1024]            16777216 B @ 0
  // Hb bf16 [129][32][1024]             8454144 B @ 16777216
  // Wb bf16 [8192][1024]               16777216 B @ 25231360
  // Rb bf16 [1024][1024]                2097152 B @ 42008576
  // Wdiag f32 [1024]                       4096 B @ 44105728
  // Hf f32 ping-pong 2x[32][1024]      2x131072 B @ 44109824
  char* ws = (char*)d_ws;
  float* X = (float*)ws;
  short* Hb = (short*)(ws + 16777216);
  short* Wb = (short*)(ws + 25231360);
  short* Rb = (short*)(ws + 42008576);
  float* Wdiag = (float*)(ws + 44105728);
  float* Hf0 = (float*)(ws + 44109824);
  float* Hf1 = (float*)(ws + 44240896);

  conv_bf16_k<<<dim3(8192), dim3(256), 0, stream>>>(W_ho, Wb, (V_ * D_) / 4);
  conv_whh<<<dim3(4096), dim3(256), 0, stream>>>(W_hh, Rb, Wdiag);
  init_h<<<dim3(128), dim3(256), 0, stream>>>(h0, Hf0, Hb);
  xgather<<<dim3(16384), dim3(256), 0, stream>>>(idx, W_ih, b_ih, b_hh, X);

  for (int t = 0; t < T_; ++t) {
    const short* Hbp = Hb + (size_t)t * B_ * D_;
    short* Hbn = Hb + (size_t)(t + 1) * B_ * D_;
    const float* Hfp = (t & 1) ? Hf1 : Hf0;
    float* Hfn = (t & 1) ? Hf0 : Hf1;
    rnn_step_mfma<<<dim3(64), dim3(64), 0, stream>>>(
        Hbp, Hfp, Rb, Wdiag, X + (size_t)t * B_ * D_, Hbn, Hfn);
  }

  // logits for step t read Hb slot t+1  ->  A = Hb + 32768
  gemm_logits<<<dim3(V_ / 128, (T_ * B_) / 128), dim3(256), 0, stream>>>(
      Hb + B_ * D_, Wb, b_o, out);
  logsoftmax<<<dim3(T_ * B_), dim3(256), 0, stream>>>(out);
}